// Round 13
// baseline (2077.083 us; speedup 1.0000x reference)
//
#include <hip/hip_runtime.h>

// HeteroGNN: 2 layers x 4 GATConv (single head), N=100000, E=800000, C=128.
// R13: half-wave conv split in agg: lanes 0-31 = conv A, 32-63 = conv B,
// 4 fp8 feats/lane (dword per row). Halves the per-edge instruction stream
// (one score path + one load instruction covers both convs). No divergence
// (uniform wave-max loop bounds); coalesced stores/atomics preserved.
// Rest as R12 (MFMA gemm_dual2, fp8 hs, binary-search counts).

#define NEG_SLOPE 0.2f

typedef __attribute__((ext_vector_type(8))) short short8v;
typedef __attribute__((ext_vector_type(4))) float float4v;
typedef __attribute__((ext_vector_type(2))) float float2v;

__device__ __forceinline__ unsigned short f2bf(float f) {
  unsigned u = __float_as_uint(f);
  unsigned r = (u + 0x7FFFu + ((u >> 16) & 1u)) >> 16;
  return (unsigned short)r;
}
__device__ __forceinline__ unsigned pack2(float a, float b) {
  return (unsigned)f2bf(a) | ((unsigned)f2bf(b) << 16);
}
__device__ __forceinline__ float bflo(unsigned u) {
  return __uint_as_float(u << 16);
}
__device__ __forceinline__ float bfhi(unsigned u) {
  return __uint_as_float(u & 0xFFFF0000u);
}
__device__ __forceinline__ int rl_i(int x, int lane) {
  return __builtin_amdgcn_readlane(x, lane);
}

// ---------- W -> bf16 transposed (Wt[n][k] = W[k][n]), 8 matrices ----------
__global__ __launch_bounds__(256) void w_to_bf16t(const float* __restrict__ W,
                                                  unsigned short* __restrict__ Wt) {
  __shared__ float buf[64][129];
  int b = blockIdx.x, t = threadIdx.x;
  const float* w = W + (size_t)b * 16384;
  unsigned short* o = Wt + (size_t)b * 16384;
  for (int h = 0; h < 2; ++h) {
    for (int i = 0; i < 32; ++i) {
      int idx = i * 256 + t;
      buf[idx >> 7][idx & 127] = w[(size_t)(h * 64 + (idx >> 7)) * 128 + (idx & 127)];
    }
    __syncthreads();
    for (int i = 0; i < 32; ++i) {
      int idx = i * 256 + t;
      o[(size_t)(idx >> 6) * 128 + h * 64 + (idx & 63)] = f2bf(buf[idx & 63][idx >> 6]);
    }
    __syncthreads();
  }
}

// ---------- precompute (Wd @ a_d) for all 8 (layer,conv) ----------
__global__ void precompute_wa(const float* __restrict__ W,
                              const float* __restrict__ att,
                              float* __restrict__ out) {
  int idx = blockIdx.x;   // 0..7
  int f = threadIdx.x;    // 0..127
  const float* w = W + (size_t)idx * 128 * 128 + (size_t)f * 128;
  const float* a = att + idx * 128;
  float s = 0.f;
  #pragma unroll 8
  for (int h = 0; h < 128; ++h) s += w[h] * a[h];
  out[idx * 128 + f] = s;
}

// ---------- args for one dual GEMM ----------
struct GemmArgs {
  const unsigned short* Wt1; const float* att1;
  unsigned char* Hb1; float* as1;
  const unsigned short* Wt2; const float* att2;
  unsigned char* Hb2; float* as2;
  const float* vdA; const float* vdB;
  float* adA; float* adB;
};

// ---------- merged MFMA dual GEMM (fp8 hs out, f32 accum) ----------
template <int XBF16>
__global__ __launch_bounds__(256) void gemm_dual2(
    const void* __restrict__ X0, const void* __restrict__ X1,
    GemmArgs Ga, GemmArgs Gb, int M) {
  __shared__ unsigned short Xt[64][136];    // [row][k], bf16, padded
  __shared__ unsigned short Wt[128][136];   // [n][k], bf16, padded
  const int t = threadIdx.x;
  const int row0 = blockIdx.x * 64;
  const void* Xv = blockIdx.y ? X1 : X0;
  const GemmArgs& G = blockIdx.y ? Gb : Ga;

  // stage X tile as bf16
  {
    int r = t >> 2;
    int cq = (t & 3) * 32;
    int gr = row0 + r;
    if (gr >= M) gr = M - 1;
    if (XBF16) {
      const unsigned short* Xb = (const unsigned short*)Xv;
      const uint4* src = (const uint4*)(Xb + (size_t)gr * 128 + cq);
      #pragma unroll
      for (int i = 0; i < 4; ++i) *(uint4*)&Xt[r][cq + i * 8] = src[i];
    } else {
      const float* Xf = (const float*)Xv;
      const float4* src = (const float4*)(Xf + (size_t)gr * 128 + cq);
      #pragma unroll
      for (int i = 0; i < 8; ++i) {
        float4 v = src[i];
        uint2 u;
        u.x = pack2(v.x, v.y);
        u.y = pack2(v.z, v.w);
        *(uint2*)&Xt[r][cq + i * 4] = u;
      }
    }
  }
  // stage W1
  {
    int n = t >> 1;
    int kh = (t & 1) * 64;
    const uint4* src = (const uint4*)(G.Wt1 + (size_t)n * 128 + kh);
    #pragma unroll
    for (int i = 0; i < 8; ++i) *(uint4*)&Wt[n][kh + i * 8] = src[i];
  }
  __syncthreads();

  // ad epilogue: rows 0..63 dot vdA (threads 0-63) / vdB (threads 64-127)
  if (t < 128) {
    int r = t & 63;
    const float* vd = (t < 64) ? G.vdA : G.vdB;
    float* adout = (t < 64) ? G.adA : G.adB;
    float sum = 0.f;
    #pragma unroll 4
    for (int k8 = 0; k8 < 16; ++k8) {
      uint4 u = *(const uint4*)&Xt[r][k8 * 8];
      const float* v = vd + k8 * 8;
      sum = fmaf(bflo(u.x), v[0], sum);
      sum = fmaf(bfhi(u.x), v[1], sum);
      sum = fmaf(bflo(u.y), v[2], sum);
      sum = fmaf(bfhi(u.y), v[3], sum);
      sum = fmaf(bflo(u.z), v[4], sum);
      sum = fmaf(bfhi(u.z), v[5], sum);
      sum = fmaf(bflo(u.w), v[6], sum);
      sum = fmaf(bfhi(u.w), v[7], sum);
    }
    int gr = row0 + r;
    if (gr < M) adout[gr] = sum;
  }

  const int lane = t & 63;
  const int wv = t >> 6;          // wave 0..3 -> rows ws..ws+15
  const int m = lane & 15;        // A-row / B-col / D-col
  const int g = lane >> 4;        // k-chunk group; D-rows g*4..g*4+3
  const int ws = wv * 16;

  for (int ww = 0; ww < 2; ++ww) {
    if (ww == 1) {
      __syncthreads();            // everyone done with W1
      int n = t >> 1;
      int kh = (t & 1) * 64;
      const uint4* src = (const uint4*)(G.Wt2 + (size_t)n * 128 + kh);
      #pragma unroll
      for (int i = 0; i < 8; ++i) *(uint4*)&Wt[n][kh + i * 8] = src[i];
      __syncthreads();
    }
    const float* att = ww ? G.att2 : G.att1;
    unsigned char* Hb = ww ? G.Hb2 : G.Hb1;
    float* as_ = ww ? G.as2 : G.as1;

    float4v acc[8];
    float4v z = {0.f, 0.f, 0.f, 0.f};
    #pragma unroll
    for (int nt = 0; nt < 8; ++nt) acc[nt] = z;

    #pragma unroll
    for (int ks = 0; ks < 4; ++ks) {
      short8v a = *(const short8v*)&Xt[ws + m][ks * 32 + g * 8];
      #pragma unroll
      for (int nt = 0; nt < 8; ++nt) {
        short8v b = *(const short8v*)&Wt[nt * 16 + m][ks * 32 + g * 8];
        acc[nt] = __builtin_amdgcn_mfma_f32_16x16x32_bf16(a, b, acc[nt], 0, 0, 0);
      }
    }

    // as epilogue: as[row] = sum_col acc[row][col]*att[col]
    {
      float attv[8];
      #pragma unroll
      for (int nt = 0; nt < 8; ++nt) attv[nt] = att[nt * 16 + m];
      #pragma unroll
      for (int r = 0; r < 4; ++r) {
        float s = 0.f;
        #pragma unroll
        for (int nt = 0; nt < 8; ++nt) s = fmaf(acc[nt][r], attv[nt], s);
        #pragma unroll
        for (int off = 1; off < 16; off <<= 1) s += __shfl_xor(s, off);
        if (m == 0) {
          int grow = row0 + ws + g * 4 + r;
          if (grow < M) as_[grow] = s;
        }
      }
    }

    // hs store: fp8 e4m3, pack adjacent-col pairs via lane shuffle
    #pragma unroll
    for (int nt = 0; nt < 8; ++nt) {
      #pragma unroll
      for (int r = 0; r < 4; ++r) {
        float v = acc[nt][r];
        float vn = __shfl_xor(v, 1);
        if ((m & 1) == 0) {
          int grow = row0 + ws + g * 4 + r;
          if (grow < M) {
            int pk = __builtin_amdgcn_cvt_pk_fp8_f32(v, vn, 0, false);
            *(unsigned short*)(Hb + (size_t)grow * 128 + nt * 16 + m) =
                (unsigned short)(pk & 0xFFFF);
          }
        }
      }
    }
  }
}

// ---------- CSR build ----------
__global__ void hist4(const int* __restrict__ e0, const int* __restrict__ e1,
                      const int* __restrict__ e2, const int* __restrict__ e3,
                      int E, int* __restrict__ deg, int N) {
  int t = blockIdx.y;
  const int* ei = (t == 0) ? e0 : (t == 1) ? e1 : (t == 2) ? e2 : e3;
  int stride = gridDim.x * 256;
  for (int i = blockIdx.x * 256 + threadIdx.x; i < E; i += stride)
    atomicAdd(&deg[t * N + ei[E + i]], 1);
}

__global__ __launch_bounds__(1024) void scan4(const int* __restrict__ deg,
                                              int* __restrict__ rowptr, int N) {
  __shared__ int sums[1024];
  int t = threadIdx.x;
  int ty = blockIdx.x;
  const int* d = deg + (size_t)ty * N;
  int* rp = rowptr + (size_t)ty * (N + 1);
  int chunk = (N + 1023) / 1024;
  int lo = t * chunk;
  int hi = lo + chunk; if (hi > N) hi = N; if (lo > N) lo = N;
  int s = 0;
  for (int i = lo; i < hi; ++i) s += d[i];
  sums[t] = s;
  __syncthreads();
  for (int off = 1; off < 1024; off <<= 1) {
    int add = (t >= off) ? sums[t - off] : 0;
    __syncthreads();
    sums[t] += add;
    __syncthreads();
  }
  int run = (t == 0) ? 0 : sums[t - 1];
  for (int i = lo; i < hi; ++i) {
    rp[i] = run;
    run += d[i];
  }
  if (t == 1023) rp[N] = sums[1023];
}

__global__ void fill4(const int* __restrict__ e0, const int* __restrict__ e1,
                      const int* __restrict__ e2, const int* __restrict__ e3,
                      int E, const int* __restrict__ rowptr,
                      int* __restrict__ fill, int* __restrict__ csrc, int N) {
  int t = blockIdx.y;
  const int* ei = (t == 0) ? e0 : (t == 1) ? e1 : (t == 2) ? e2 : e3;
  int stride = gridDim.x * 256;
  for (int i = blockIdx.x * 256 + threadIdx.x; i < E; i += stride) {
    int d = ei[E + i];
    int s = ei[i];
    int pos = rowptr[(size_t)t * (N + 1) + d] + atomicAdd(&fill[t * N + d], 1);
    csrc[(size_t)t * E + pos] = s;
  }
}

// ---------- args bundle for one conv-pair ----------
struct PairArgs {
  const int* rA; const int* sA; const unsigned char* hA;
  const float* asA; const float* adA;
  const int* rB; const int* sB; const unsigned char* hB;
  const float* asB; const float* adB;
  const float* biasA; const float* biasB;
};

// ---------- half-wave dual-conv softmax agg ----------
// lanes 0-31: conv A; lanes 32-63: conv B. Each lane owns 4 fp8 feats
// (dword per row). Returns summed A+B feats (valid on lanes 0-31; feats
// 4*hl .. 4*hl+3). No divergence: loop bounds are wave-uniform maxima.
__device__ __forceinline__ void agg_pair_hw(const PairArgs& P, int n, int lane,
                                            float* accv) {
  const int half = lane >> 5;
  const int hl = lane & 31;
  const int hbase = lane & 32;       // shfl base for my half
  const int* rp = half ? P.rB : P.rA;
  const int* sc = half ? P.sB : P.sA;
  const unsigned char* hp = half ? P.hB : P.hA;
  const float* asp = half ? P.asB : P.asA;
  const float ad = (half ? P.adB : P.adA)[n];
  int beg = rp[n], end = rp[n + 1];
  float lsum = 0.f;
  float a0 = 0.f, a1 = 0.f, a2 = 0.f, a3 = 0.f;
  int c = beg;
  while (true) {
    int cl = end - c;
    cl = cl < 0 ? 0 : (cl > 32 ? 32 : cl);
    int cntA = rl_i(cl, 0);
    int cntB = rl_i(cl, 32);
    int cnt = cntA > cntB ? cntA : cntB;
    if (cnt == 0) break;
    int k = c + hl;
    bool valid = k < end;
    int s = valid ? sc[k] : 0;
    float e = valid ? (asp[s] + ad) : 0.f;
    e = e > 0.f ? e : NEG_SLOPE * e;
    float p = valid ? __expf(e) : 0.f;
    for (int base = 0; base < cnt; base += 8) {
      int i0 = hbase + base;
      float q0 = __shfl(p, i0 + 0), q1 = __shfl(p, i0 + 1);
      float q2 = __shfl(p, i0 + 2), q3 = __shfl(p, i0 + 3);
      float q4 = __shfl(p, i0 + 4), q5 = __shfl(p, i0 + 5);
      float q6 = __shfl(p, i0 + 6), q7 = __shfl(p, i0 + 7);
      int t0 = __shfl(s, i0 + 0), t1 = __shfl(s, i0 + 1);
      int t2 = __shfl(s, i0 + 2), t3 = __shfl(s, i0 + 3);
      int t4 = __shfl(s, i0 + 4), t5 = __shfl(s, i0 + 5);
      int t6 = __shfl(s, i0 + 6), t7 = __shfl(s, i0 + 7);
      unsigned u0 = *(const unsigned*)(hp + (size_t)t0 * 128 + hl * 4);
      unsigned u1 = *(const unsigned*)(hp + (size_t)t1 * 128 + hl * 4);
      unsigned u2 = *(const unsigned*)(hp + (size_t)t2 * 128 + hl * 4);
      unsigned u3 = *(const unsigned*)(hp + (size_t)t3 * 128 + hl * 4);
      unsigned u4 = *(const unsigned*)(hp + (size_t)t4 * 128 + hl * 4);
      unsigned u5 = *(const unsigned*)(hp + (size_t)t5 * 128 + hl * 4);
      unsigned u6 = *(const unsigned*)(hp + (size_t)t6 * 128 + hl * 4);
      unsigned u7 = *(const unsigned*)(hp + (size_t)t7 * 128 + hl * 4);
      lsum += ((q0 + q1) + (q2 + q3)) + ((q4 + q5) + (q6 + q7));
      #define ACC4(q, u) {                                              \
        float2v lo = __builtin_amdgcn_cvt_pk_f32_fp8((int)(u), false);  \
        float2v hi = __builtin_amdgcn_cvt_pk_f32_fp8((int)(u), true);   \
        a0 = fmaf(q, lo[0], a0); a1 = fmaf(q, lo[1], a1);               \
        a2 = fmaf(q, hi[0], a2); a3 = fmaf(q, hi[1], a3); }
      ACC4(q0, u0) ACC4(q1, u1) ACC4(q2, u2) ACC4(q3, u3)
      ACC4(q4, u4) ACC4(q5, u5) ACC4(q6, u6) ACC4(q7, u7)
      #undef ACC4
    }
    c += 32;
  }
  float inv = 1.f / fmaxf(lsum, 1e-16f);
  a0 *= inv; a1 *= inv; a2 *= inv; a3 *= inv;
  // cross-half merge: A + B per feature
  a0 += __shfl_xor(a0, 32);
  a1 += __shfl_xor(a1, 32);
  a2 += __shfl_xor(a2, 32);
  a3 += __shfl_xor(a3, 32);
  accv[0] = a0; accv[1] = a1; accv[2] = a2; accv[3] = a3;
}

// ---------- merged layer-1: both pairs in one dispatch (blockIdx.y) ----------
__global__ __launch_bounds__(256) void agg_store2(
    PairArgs P0, unsigned short* __restrict__ out0,
    PairArgs P1, unsigned short* __restrict__ out1, int N) {
  int wave = (blockIdx.x * 256 + threadIdx.x) >> 6;
  int lane = threadIdx.x & 63;
  if (wave >= N) return;
  const PairArgs& P = blockIdx.y ? P1 : P0;
  unsigned short* out = blockIdx.y ? out1 : out0;
  float v[4];
  agg_pair_hw(P, wave, lane, v);
  if (lane < 32) {
    int hl = lane;
    float4 ba = *(const float4*)(P.biasA + hl * 4);
    float4 bb = *(const float4*)(P.biasB + hl * 4);
    float v0 = tanhf(v[0] + ba.x + bb.x);
    float v1 = tanhf(v[1] + ba.y + bb.y);
    float v2 = tanhf(v[2] + ba.z + bb.z);
    float v3 = tanhf(v[3] + ba.w + bb.w);
    uint2 o;
    o.x = pack2(v0, v1);
    o.y = pack2(v2, v3);
    *(uint2*)(out + (size_t)wave * 128 + hl * 4) = o;
  }
}

// ---------- merged layer-2: both pairs, pooled directly (atomic) ----------
__global__ __launch_bounds__(256) void agg_pool2(
    PairArgs P0, const int* __restrict__ batch0, float* __restrict__ pool0,
    PairArgs P1, const int* __restrict__ batch1, float* __restrict__ pool1,
    int N) {
  int wave = (blockIdx.x * 256 + threadIdx.x) >> 6;
  int lane = threadIdx.x & 63;
  if (wave >= N) return;
  const PairArgs& P = blockIdx.y ? P1 : P0;
  const int* batch = blockIdx.y ? batch1 : batch0;
  float* pool = blockIdx.y ? pool1 : pool0;
  float v[4];
  agg_pair_hw(P, wave, lane, v);
  if (lane < 32) {
    int hl = lane;
    float4 ba = *(const float4*)(P.biasA + hl * 4);
    float4 bb = *(const float4*)(P.biasB + hl * 4);
    int bb_idx = batch[wave];
    float* p = pool + (size_t)bb_idx * 128 + hl * 4;
    unsafeAtomicAdd(p + 0, tanhf(v[0] + ba.x + bb.x));
    unsafeAtomicAdd(p + 1, tanhf(v[1] + ba.y + bb.y));
    unsafeAtomicAdd(p + 2, tanhf(v[2] + ba.z + bb.z));
    unsafeAtomicAdd(p + 3, tanhf(v[3] + ba.w + bb.w));
  }
}

// ---------- final: counts via binary search over the SORTED batch arrays ----
__device__ __forceinline__ int lower_bound_i(const int* __restrict__ a, int n,
                                             int v) {
  int lo = 0, hi = n;
  while (lo < hi) {
    int mid = (lo + hi) >> 1;
    if (a[mid] < v) lo = mid + 1; else hi = mid;
  }
  return lo;
}

__global__ void final_k(const float* __restrict__ pool_i,
                        const int* __restrict__ batch_i,
                        const float* __restrict__ pool_j,
                        const int* __restrict__ batch_j, int N,
                        const float* __restrict__ lin_w,
                        const float* __restrict__ lin_b,
                        float* __restrict__ out) {
  int b = threadIdx.x;  // 256
  float ci = (float)(lower_bound_i(batch_i, N, b + 1) -
                     lower_bound_i(batch_i, N, b));
  float cj = (float)(lower_bound_i(batch_j, N, b + 1) -
                     lower_bound_i(batch_j, N, b));
  ci = fmaxf(ci, 1.f);
  cj = fmaxf(cj, 1.f);
  float acc = 0.f;
  #pragma unroll 4
  for (int f = 0; f < 128; ++f) {
    float x = 0.5f * (pool_i[(size_t)b * 128 + f] / ci +
                      pool_j[(size_t)b * 128 + f] / cj);
    acc += x * lin_w[f];
  }
  acc += lin_b[0];
  out[b] = 1.f / (1.f + __expf(-acc));
}

extern "C" void kernel_launch(void* const* d_in, const int* in_sizes, int n_in,
                              void* d_out, int out_size, void* d_ws,
                              size_t ws_size, hipStream_t stream) {
  const float* x_i = (const float*)d_in[0];
  const float* x_j = (const float*)d_in[1];
  const int* ei_arr[4] = {(const int*)d_in[2], (const int*)d_in[3],
                          (const int*)d_in[4], (const int*)d_in[5]};  // ii,jj,ij,ji
  const int* batch_i = (const int*)d_in[6];
  const int* batch_j = (const int*)d_in[7];
  const float* Ws = (const float*)d_in[8];
  const float* Wd = (const float*)d_in[9];
  const float* att_s = (const float*)d_in[10];
  const float* att_d = (const float*)d_in[11];
  const float* bias = (const float*)d_in[12];
  const float* lin_w = (const float*)d_in[13];
  const float* lin_b = (const float*)d_in[14];
  float* out = (float*)d_out;

  const int N = in_sizes[0] / 128;   // 100000
  const int E = in_sizes[2] / 2;     // 800000
  const size_t NF = (size_t)N * 128;

  char* w = (char*)d_ws;
  auto alloc = [&](size_t bytes) {
    char* p = w;
    w += (bytes + 255) & ~(size_t)255;
    return p;
  };
  unsigned short* bufA_i = (unsigned short*)alloc(NF * 2);
  unsigned short* bufA_j = (unsigned short*)alloc(NF * 2);
  unsigned char* hsb[4];
  for (int c = 0; c < 4; ++c) hsb[c] = (unsigned char*)alloc(NF);
  int* csrc = (int*)alloc((size_t)4 * E * 4);
  int* rowptr = (int*)alloc((size_t)4 * (N + 1) * 4);
  int* deg = (int*)alloc((size_t)4 * N * 4);
  int* fillc = (int*)alloc((size_t)4 * N * 4);
  float* asb[4];
  for (int c = 0; c < 4; ++c) asb[c] = (float*)alloc((size_t)N * 4);
  float* adb[4];
  for (int c = 0; c < 4; ++c) adb[c] = (float*)alloc((size_t)N * 4);
  float* wdad = (float*)alloc(8 * 128 * 4);
  unsigned short* Wst = (unsigned short*)alloc(8 * 16384 * 2);
  float* pool = (float*)alloc(2 * 256 * 128 * 4);
  float* pool_i = pool;
  float* pool_j = pool + 256 * 128;

  // ---- one-time prep ----
  w_to_bf16t<<<8, 256, 0, stream>>>(Ws, Wst);
  precompute_wa<<<8, 128, 0, stream>>>(Wd, att_d, wdad);

  // ---- CSR build (edge lists shared by both layers) ----
  hipMemsetAsync(deg, 0, (size_t)4 * N * 4, stream);
  hipMemsetAsync(fillc, 0, (size_t)4 * N * 4, stream);
  dim3 egrid(512, 4);
  hist4<<<egrid, 256, 0, stream>>>(ei_arr[0], ei_arr[1], ei_arr[2], ei_arr[3],
                                   E, deg, N);
  scan4<<<4, 1024, 0, stream>>>(deg, rowptr, N);
  fill4<<<egrid, 256, 0, stream>>>(ei_arr[0], ei_arr[1], ei_arr[2], ei_arr[3],
                                   E, rowptr, fillc, csrc, N);

  hipMemsetAsync(pool, 0, 2 * 256 * 128 * 4, stream);

  const int gemm_blocks = (N + 63) / 64;
  const int nodew_blocks = (N + 3) / 4;   // one wave per node

  // conv c0 = ii (src i, dst i); c1 = jj (src j, dst j);
  // conv c2 = ij (src i, dst j); c3 = ji (src j, dst i).
  // pair0: out_i <- convs {c0, c3}; pair1: out_j <- {c1, c2}.
  for (int l = 0; l < 2; ++l) {
    const void* cur_i = (l == 0) ? (const void*)x_i : (const void*)bufA_i;
    const void* cur_j = (l == 0) ? (const void*)x_j : (const void*)bufA_j;
    const size_t L = (size_t)l * 4;

    GemmArgs Ga = {Wst + (L + 0) * 16384, att_s + (L + 0) * 128, hsb[0], asb[0],
                   Wst + (L + 2) * 16384, att_s + (L + 2) * 128, hsb[2], asb[2],
                   wdad + (L + 0) * 128, wdad + (L + 3) * 128, adb[0], adb[3]};
    GemmArgs Gb = {Wst + (L + 1) * 16384, att_s + (L + 1) * 128, hsb[1], asb[1],
                   Wst + (L + 3) * 16384, att_s + (L + 3) * 128, hsb[3], asb[3],
                   wdad + (L + 1) * 128, wdad + (L + 2) * 128, adb[1], adb[2]};
    dim3 ggrid(gemm_blocks, 2);
    if (l == 0) {
      gemm_dual2<0><<<ggrid, 256, 0, stream>>>(cur_i, cur_j, Ga, Gb, N);
    } else {
      gemm_dual2<1><<<ggrid, 256, 0, stream>>>(cur_i, cur_j, Ga, Gb, N);
    }

    PairArgs P0 = {rowptr + (size_t)0 * (N + 1), csrc + (size_t)0 * E, hsb[0],
                   asb[0], adb[0],
                   rowptr + (size_t)3 * (N + 1), csrc + (size_t)3 * E, hsb[3],
                   asb[3], adb[3],
                   bias + (L + 0) * 128, bias + (L + 3) * 128};
    PairArgs P1 = {rowptr + (size_t)1 * (N + 1), csrc + (size_t)1 * E, hsb[1],
                   asb[1], adb[1],
                   rowptr + (size_t)2 * (N + 1), csrc + (size_t)2 * E, hsb[2],
                   asb[2], adb[2],
                   bias + (L + 1) * 128, bias + (L + 2) * 128};

    dim3 agrid(nodew_blocks, 2);
    if (l == 0) {
      agg_store2<<<agrid, 256, 0, stream>>>(P0, bufA_i, P1, bufA_j, N);
    } else {
      agg_pool2<<<agrid, 256, 0, stream>>>(P0, batch_i, pool_i, P1, batch_j,
                                           pool_j, N);
    }
  }

  final_k<<<1, 256, 0, stream>>>(pool_i, batch_i, pool_j, batch_j, N, lin_w,
                                 lin_b, out);
}

// Round 14
// 1105.214 us; speedup vs baseline: 1.8793x; 1.8793x over previous
//
#include <hip/hip_runtime.h>

// HeteroGNN: 2 layers x 4 GATConv (single head), N=100000, E=800000, C=128.
// R14: exact R12 structure (best, 1039us) + R10's precomputed {s,p} CSR
// payload: edge_p4 computes p=exp(leaky(as[src]+ad[dst])) coalesced and
// scatters uint2{s,p} into CSR order; agg loop loads one coalesced 8B sp
// per slot (removes as-gather/leaky/exp from the loop, now that R12's
// counters show issue-boundedness). R13's half-wave split reverted
// (3rd failed lane-split restructure: FETCH 2.5x, WRITE 14x).

#define NEG_SLOPE 0.2f

typedef __attribute__((ext_vector_type(8))) short short8v;
typedef __attribute__((ext_vector_type(4))) float float4v;
typedef __attribute__((ext_vector_type(2))) float float2v;

__device__ __forceinline__ unsigned short f2bf(float f) {
  unsigned u = __float_as_uint(f);
  unsigned r = (u + 0x7FFFu + ((u >> 16) & 1u)) >> 16;
  return (unsigned short)r;
}
__device__ __forceinline__ unsigned pack2(float a, float b) {
  return (unsigned)f2bf(a) | ((unsigned)f2bf(b) << 16);
}
__device__ __forceinline__ float bflo(unsigned u) {
  return __uint_as_float(u << 16);
}
__device__ __forceinline__ float bfhi(unsigned u) {
  return __uint_as_float(u & 0xFFFF0000u);
}
__device__ __forceinline__ float rl_f(float x, int lane) {
  return __int_as_float(__builtin_amdgcn_readlane(__float_as_int(x), lane));
}
__device__ __forceinline__ int rl_i(int x, int lane) {
  return __builtin_amdgcn_readlane(x, lane);
}

// ---------- W -> bf16 transposed (Wt[n][k] = W[k][n]), 8 matrices ----------
__global__ __launch_bounds__(256) void w_to_bf16t(const float* __restrict__ W,
                                                  unsigned short* __restrict__ Wt) {
  __shared__ float buf[64][129];
  int b = blockIdx.x, t = threadIdx.x;
  const float* w = W + (size_t)b * 16384;
  unsigned short* o = Wt + (size_t)b * 16384;
  for (int h = 0; h < 2; ++h) {
    for (int i = 0; i < 32; ++i) {
      int idx = i * 256 + t;
      buf[idx >> 7][idx & 127] = w[(size_t)(h * 64 + (idx >> 7)) * 128 + (idx & 127)];
    }
    __syncthreads();
    for (int i = 0; i < 32; ++i) {
      int idx = i * 256 + t;
      o[(size_t)(idx >> 6) * 128 + h * 64 + (idx & 63)] = f2bf(buf[idx & 63][idx >> 6]);
    }
    __syncthreads();
  }
}

// ---------- precompute (Wd @ a_d) for all 8 (layer,conv) ----------
__global__ void precompute_wa(const float* __restrict__ W,
                              const float* __restrict__ att,
                              float* __restrict__ out) {
  int idx = blockIdx.x;   // 0..7
  int f = threadIdx.x;    // 0..127
  const float* w = W + (size_t)idx * 128 * 128 + (size_t)f * 128;
  const float* a = att + idx * 128;
  float s = 0.f;
  #pragma unroll 8
  for (int h = 0; h < 128; ++h) s += w[h] * a[h];
  out[idx * 128 + f] = s;
}

// ---------- args for one dual GEMM ----------
struct GemmArgs {
  const unsigned short* Wt1; const float* att1;
  unsigned char* Hb1; float* as1;
  const unsigned short* Wt2; const float* att2;
  unsigned char* Hb2; float* as2;
  const float* vdA; const float* vdB;
  float* adA; float* adB;
};

// ---------- merged MFMA dual GEMM (fp8 hs out, f32 accum) ----------
template <int XBF16>
__global__ __launch_bounds__(256) void gemm_dual2(
    const void* __restrict__ X0, const void* __restrict__ X1,
    GemmArgs Ga, GemmArgs Gb, int M) {
  __shared__ unsigned short Xt[64][136];    // [row][k], bf16, padded
  __shared__ unsigned short Wt[128][136];   // [n][k], bf16, padded
  const int t = threadIdx.x;
  const int row0 = blockIdx.x * 64;
  const void* Xv = blockIdx.y ? X1 : X0;
  const GemmArgs& G = blockIdx.y ? Gb : Ga;

  // stage X tile as bf16
  {
    int r = t >> 2;
    int cq = (t & 3) * 32;
    int gr = row0 + r;
    if (gr >= M) gr = M - 1;
    if (XBF16) {
      const unsigned short* Xb = (const unsigned short*)Xv;
      const uint4* src = (const uint4*)(Xb + (size_t)gr * 128 + cq);
      #pragma unroll
      for (int i = 0; i < 4; ++i) *(uint4*)&Xt[r][cq + i * 8] = src[i];
    } else {
      const float* Xf = (const float*)Xv;
      const float4* src = (const float4*)(Xf + (size_t)gr * 128 + cq);
      #pragma unroll
      for (int i = 0; i < 8; ++i) {
        float4 v = src[i];
        uint2 u;
        u.x = pack2(v.x, v.y);
        u.y = pack2(v.z, v.w);
        *(uint2*)&Xt[r][cq + i * 4] = u;
      }
    }
  }
  // stage W1
  {
    int n = t >> 1;
    int kh = (t & 1) * 64;
    const uint4* src = (const uint4*)(G.Wt1 + (size_t)n * 128 + kh);
    #pragma unroll
    for (int i = 0; i < 8; ++i) *(uint4*)&Wt[n][kh + i * 8] = src[i];
  }
  __syncthreads();

  // ad epilogue: rows 0..63 dot vdA (threads 0-63) / vdB (threads 64-127)
  if (t < 128) {
    int r = t & 63;
    const float* vd = (t < 64) ? G.vdA : G.vdB;
    float* adout = (t < 64) ? G.adA : G.adB;
    float sum = 0.f;
    #pragma unroll 4
    for (int k8 = 0; k8 < 16; ++k8) {
      uint4 u = *(const uint4*)&Xt[r][k8 * 8];
      const float* v = vd + k8 * 8;
      sum = fmaf(bflo(u.x), v[0], sum);
      sum = fmaf(bfhi(u.x), v[1], sum);
      sum = fmaf(bflo(u.y), v[2], sum);
      sum = fmaf(bfhi(u.y), v[3], sum);
      sum = fmaf(bflo(u.z), v[4], sum);
      sum = fmaf(bfhi(u.z), v[5], sum);
      sum = fmaf(bflo(u.w), v[6], sum);
      sum = fmaf(bfhi(u.w), v[7], sum);
    }
    int gr = row0 + r;
    if (gr < M) adout[gr] = sum;
  }

  const int lane = t & 63;
  const int wv = t >> 6;          // wave 0..3 -> rows ws..ws+15
  const int m = lane & 15;        // A-row / B-col / D-col
  const int g = lane >> 4;        // k-chunk group; D-rows g*4..g*4+3
  const int ws = wv * 16;

  for (int ww = 0; ww < 2; ++ww) {
    if (ww == 1) {
      __syncthreads();            // everyone done with W1
      int n = t >> 1;
      int kh = (t & 1) * 64;
      const uint4* src = (const uint4*)(G.Wt2 + (size_t)n * 128 + kh);
      #pragma unroll
      for (int i = 0; i < 8; ++i) *(uint4*)&Wt[n][kh + i * 8] = src[i];
      __syncthreads();
    }
    const float* att = ww ? G.att2 : G.att1;
    unsigned char* Hb = ww ? G.Hb2 : G.Hb1;
    float* as_ = ww ? G.as2 : G.as1;

    float4v acc[8];
    float4v z = {0.f, 0.f, 0.f, 0.f};
    #pragma unroll
    for (int nt = 0; nt < 8; ++nt) acc[nt] = z;

    #pragma unroll
    for (int ks = 0; ks < 4; ++ks) {
      short8v a = *(const short8v*)&Xt[ws + m][ks * 32 + g * 8];
      #pragma unroll
      for (int nt = 0; nt < 8; ++nt) {
        short8v b = *(const short8v*)&Wt[nt * 16 + m][ks * 32 + g * 8];
        acc[nt] = __builtin_amdgcn_mfma_f32_16x16x32_bf16(a, b, acc[nt], 0, 0, 0);
      }
    }

    // as epilogue: as[row] = sum_col acc[row][col]*att[col]
    {
      float attv[8];
      #pragma unroll
      for (int nt = 0; nt < 8; ++nt) attv[nt] = att[nt * 16 + m];
      #pragma unroll
      for (int r = 0; r < 4; ++r) {
        float s = 0.f;
        #pragma unroll
        for (int nt = 0; nt < 8; ++nt) s = fmaf(acc[nt][r], attv[nt], s);
        #pragma unroll
        for (int off = 1; off < 16; off <<= 1) s += __shfl_xor(s, off);
        if (m == 0) {
          int grow = row0 + ws + g * 4 + r;
          if (grow < M) as_[grow] = s;
        }
      }
    }

    // hs store: fp8 e4m3, pack adjacent-col pairs via lane shuffle
    #pragma unroll
    for (int nt = 0; nt < 8; ++nt) {
      #pragma unroll
      for (int r = 0; r < 4; ++r) {
        float v = acc[nt][r];
        float vn = __shfl_xor(v, 1);
        if ((m & 1) == 0) {
          int grow = row0 + ws + g * 4 + r;
          if (grow < M) {
            int pk = __builtin_amdgcn_cvt_pk_fp8_f32(v, vn, 0, false);
            *(unsigned short*)(Hb + (size_t)grow * 128 + nt * 16 + m) =
                (unsigned short)(pk & 0xFFFF);
          }
        }
      }
    }
  }
}

// ---------- CSR build ----------
__global__ void hist4(const int* __restrict__ e0, const int* __restrict__ e1,
                      const int* __restrict__ e2, const int* __restrict__ e3,
                      int E, int* __restrict__ deg, int N) {
  int t = blockIdx.y;
  const int* ei = (t == 0) ? e0 : (t == 1) ? e1 : (t == 2) ? e2 : e3;
  int stride = gridDim.x * 256;
  for (int i = blockIdx.x * 256 + threadIdx.x; i < E; i += stride)
    atomicAdd(&deg[t * N + ei[E + i]], 1);
}

__global__ __launch_bounds__(1024) void scan4(const int* __restrict__ deg,
                                              int* __restrict__ rowptr, int N) {
  __shared__ int sums[1024];
  int t = threadIdx.x;
  int ty = blockIdx.x;
  const int* d = deg + (size_t)ty * N;
  int* rp = rowptr + (size_t)ty * (N + 1);
  int chunk = (N + 1023) / 1024;
  int lo = t * chunk;
  int hi = lo + chunk; if (hi > N) hi = N; if (lo > N) lo = N;
  int s = 0;
  for (int i = lo; i < hi; ++i) s += d[i];
  sums[t] = s;
  __syncthreads();
  for (int off = 1; off < 1024; off <<= 1) {
    int add = (t >= off) ? sums[t - off] : 0;
    __syncthreads();
    sums[t] += add;
    __syncthreads();
  }
  int run = (t == 0) ? 0 : sums[t - 1];
  for (int i = lo; i < hi; ++i) {
    rp[i] = run;
    run += d[i];
  }
  if (t == 1023) rp[N] = sums[1023];
}

// fill: assign each edge its CSR slot (epos)
__global__ void fill4(const int* __restrict__ e0, const int* __restrict__ e1,
                      const int* __restrict__ e2, const int* __restrict__ e3,
                      int E, const int* __restrict__ rowptr,
                      int* __restrict__ fill, int* __restrict__ epos, int N) {
  int t = blockIdx.y;
  const int* ei = (t == 0) ? e0 : (t == 1) ? e1 : (t == 2) ? e2 : e3;
  int stride = gridDim.x * 256;
  for (int i = blockIdx.x * 256 + threadIdx.x; i < E; i += stride) {
    int d = ei[E + i];
    int pos = rowptr[(size_t)t * (N + 1) + d] + atomicAdd(&fill[t * N + d], 1);
    epos[(size_t)t * E + i] = pos;
  }
}

// ---------- per-layer edge pass: {s, p=exp(leaky(as+ad))} -> CSR slot --------
__global__ void edge_p4(const int* __restrict__ e0, const int* __restrict__ e1,
                        const int* __restrict__ e2, const int* __restrict__ e3,
                        int E, const int* __restrict__ epos,
                        const float* __restrict__ as0, const float* __restrict__ as1,
                        const float* __restrict__ as2, const float* __restrict__ as3,
                        const float* __restrict__ ad0, const float* __restrict__ ad1,
                        const float* __restrict__ ad2, const float* __restrict__ ad3,
                        uint2* __restrict__ spcsr) {
  int t = blockIdx.y;
  const int* ei = (t == 0) ? e0 : (t == 1) ? e1 : (t == 2) ? e2 : e3;
  const float* as_ = (t == 0) ? as0 : (t == 1) ? as1 : (t == 2) ? as2 : as3;
  const float* ad_ = (t == 0) ? ad0 : (t == 1) ? ad1 : (t == 2) ? ad2 : ad3;
  int stride = gridDim.x * 256;
  for (int i = blockIdx.x * 256 + threadIdx.x; i < E; i += stride) {
    int s = ei[i];
    int d = ei[E + i];
    float e = as_[s] + ad_[d];
    e = e > 0.f ? e : NEG_SLOPE * e;
    float p = __expf(e);
    int k = epos[(size_t)t * E + i];
    spcsr[(size_t)t * E + k] = make_uint2((unsigned)s, __float_as_uint(p));
  }
}

// ---------- args bundle for one conv-pair ----------
struct PairArgs {
  const int* rA; const uint2* spA; const unsigned char* hA;
  const int* rB; const uint2* spB; const unsigned char* hB;
  const float* biasA; const float* biasB;
};

// fp8x2 gather helper: 2 fp8 bytes -> 2 floats (HW convert)
#define GATH(P_h, idx, dst) {                                           \
  unsigned short uu = *(const unsigned short*)((P_h) + (size_t)(idx) * 128 + lane * 2); \
  dst = __builtin_amdgcn_cvt_pk_f32_fp8((int)uu, false); }

// ---------- interleaved dual-conv softmax agg (wave/node, 2 feats/lane) ------
__device__ __forceinline__ void agg_pair(const PairArgs& P, int n, int lane,
                                         float2& outA, float2& outB) {
  int begA = P.rA[n], endA = P.rA[n + 1];
  int begB = P.rB[n], endB = P.rB[n + 1];
  float lsA = 0.f, lsB = 0.f;
  float2 aA = make_float2(0.f, 0.f), aB = make_float2(0.f, 0.f);
  int cA = begA, cB = begB;
  while (cA < endA || cB < endB) {
    int kA = cA + lane, kB = cB + lane;
    uint2 vAu = (kA < endA) ? P.spA[kA] : make_uint2(0u, 0u);
    uint2 vBu = (kB < endB) ? P.spB[kB] : make_uint2(0u, 0u);
    int sA = (int)vAu.x;
    int sB = (int)vBu.x;
    float pA = __uint_as_float(vAu.y);   // 0.0f when invalid
    float pB = __uint_as_float(vBu.y);
    int cntA = endA - cA; cntA = cntA < 0 ? 0 : (cntA > 64 ? 64 : cntA);
    int cntB = endB - cB; cntB = cntB < 0 ? 0 : (cntB > 64 ? 64 : cntB);
    int cnt = cntA > cntB ? cntA : cntB;
    for (int base = 0; base < cnt; base += 8) {
      float qa0 = rl_f(pA, base + 0), qa1 = rl_f(pA, base + 1);
      float qa2 = rl_f(pA, base + 2), qa3 = rl_f(pA, base + 3);
      float qa4 = rl_f(pA, base + 4), qa5 = rl_f(pA, base + 5);
      float qa6 = rl_f(pA, base + 6), qa7 = rl_f(pA, base + 7);
      float qb0 = rl_f(pB, base + 0), qb1 = rl_f(pB, base + 1);
      float qb2 = rl_f(pB, base + 2), qb3 = rl_f(pB, base + 3);
      float qb4 = rl_f(pB, base + 4), qb5 = rl_f(pB, base + 5);
      float qb6 = rl_f(pB, base + 6), qb7 = rl_f(pB, base + 7);
      int ta0 = rl_i(sA, base + 0), ta1 = rl_i(sA, base + 1);
      int ta2 = rl_i(sA, base + 2), ta3 = rl_i(sA, base + 3);
      int ta4 = rl_i(sA, base + 4), ta5 = rl_i(sA, base + 5);
      int ta6 = rl_i(sA, base + 6), ta7 = rl_i(sA, base + 7);
      int tb0 = rl_i(sB, base + 0), tb1 = rl_i(sB, base + 1);
      int tb2 = rl_i(sB, base + 2), tb3 = rl_i(sB, base + 3);
      int tb4 = rl_i(sB, base + 4), tb5 = rl_i(sB, base + 5);
      int tb6 = rl_i(sB, base + 6), tb7 = rl_i(sB, base + 7);
      float2v ha0, ha1, ha2, ha3, ha4, ha5, ha6, ha7;
      float2v hb0, hb1, hb2, hb3, hb4, hb5, hb6, hb7;
      GATH(P.hA, ta0, ha0) GATH(P.hA, ta1, ha1)
      GATH(P.hA, ta2, ha2) GATH(P.hA, ta3, ha3)
      GATH(P.hA, ta4, ha4) GATH(P.hA, ta5, ha5)
      GATH(P.hA, ta6, ha6) GATH(P.hA, ta7, ha7)
      GATH(P.hB, tb0, hb0) GATH(P.hB, tb1, hb1)
      GATH(P.hB, tb2, hb2) GATH(P.hB, tb3, hb3)
      GATH(P.hB, tb4, hb4) GATH(P.hB, tb5, hb5)
      GATH(P.hB, tb6, hb6) GATH(P.hB, tb7, hb7)
      lsA += ((qa0 + qa1) + (qa2 + qa3)) + ((qa4 + qa5) + (qa6 + qa7));
      lsB += ((qb0 + qb1) + (qb2 + qb3)) + ((qb4 + qb5) + (qb6 + qb7));
      aA.x = fmaf(qa0, ha0[0], aA.x); aA.y = fmaf(qa0, ha0[1], aA.y);
      aA.x = fmaf(qa1, ha1[0], aA.x); aA.y = fmaf(qa1, ha1[1], aA.y);
      aA.x = fmaf(qa2, ha2[0], aA.x); aA.y = fmaf(qa2, ha2[1], aA.y);
      aA.x = fmaf(qa3, ha3[0], aA.x); aA.y = fmaf(qa3, ha3[1], aA.y);
      aA.x = fmaf(qa4, ha4[0], aA.x); aA.y = fmaf(qa4, ha4[1], aA.y);
      aA.x = fmaf(qa5, ha5[0], aA.x); aA.y = fmaf(qa5, ha5[1], aA.y);
      aA.x = fmaf(qa6, ha6[0], aA.x); aA.y = fmaf(qa6, ha6[1], aA.y);
      aA.x = fmaf(qa7, ha7[0], aA.x); aA.y = fmaf(qa7, ha7[1], aA.y);
      aB.x = fmaf(qb0, hb0[0], aB.x); aB.y = fmaf(qb0, hb0[1], aB.y);
      aB.x = fmaf(qb1, hb1[0], aB.x); aB.y = fmaf(qb1, hb1[1], aB.y);
      aB.x = fmaf(qb2, hb2[0], aB.x); aB.y = fmaf(qb2, hb2[1], aB.y);
      aB.x = fmaf(qb3, hb3[0], aB.x); aB.y = fmaf(qb3, hb3[1], aB.y);
      aB.x = fmaf(qb4, hb4[0], aB.x); aB.y = fmaf(qb4, hb4[1], aB.y);
      aB.x = fmaf(qb5, hb5[0], aB.x); aB.y = fmaf(qb5, hb5[1], aB.y);
      aB.x = fmaf(qb6, hb6[0], aB.x); aB.y = fmaf(qb6, hb6[1], aB.y);
      aB.x = fmaf(qb7, hb7[0], aB.x); aB.y = fmaf(qb7, hb7[1], aB.y);
    }
    cA += 64;
    cB += 64;
  }
  float invA = 1.f / fmaxf(lsA, 1e-16f);
  float invB = 1.f / fmaxf(lsB, 1e-16f);
  outA = make_float2(aA.x * invA, aA.y * invA);
  outB = make_float2(aB.x * invB, aB.y * invB);
}

// ---------- merged layer-1: both pairs in one dispatch (blockIdx.y) ----------
__global__ __launch_bounds__(256) void agg_store2(
    PairArgs P0, unsigned short* __restrict__ out0,
    PairArgs P1, unsigned short* __restrict__ out1, int N) {
  int wave = (blockIdx.x * 256 + threadIdx.x) >> 6;
  int lane = threadIdx.x & 63;
  if (wave >= N) return;
  const PairArgs& P = blockIdx.y ? P1 : P0;
  unsigned short* out = blockIdx.y ? out1 : out0;
  float2 a, b;
  agg_pair(P, wave, lane, a, b);
  float2 b1 = *(const float2*)(P.biasA + lane * 2);
  float2 b2 = *(const float2*)(P.biasB + lane * 2);
  float vx = tanhf(a.x + b.x + b1.x + b2.x);
  float vy = tanhf(a.y + b.y + b1.y + b2.y);
  *(unsigned*)(out + (size_t)wave * 128 + lane * 2) = pack2(vx, vy);
}

// ---------- merged layer-2: both pairs, pooled directly (atomic) ----------
__global__ __launch_bounds__(256) void agg_pool2(
    PairArgs P0, const int* __restrict__ batch0, float* __restrict__ pool0,
    PairArgs P1, const int* __restrict__ batch1, float* __restrict__ pool1,
    int N) {
  int wave = (blockIdx.x * 256 + threadIdx.x) >> 6;
  int lane = threadIdx.x & 63;
  if (wave >= N) return;
  const PairArgs& P = blockIdx.y ? P1 : P0;
  const int* batch = blockIdx.y ? batch1 : batch0;
  float* pool = blockIdx.y ? pool1 : pool0;
  float2 a, b;
  agg_pair(P, wave, lane, a, b);
  float2 b1 = *(const float2*)(P.biasA + lane * 2);
  float2 b2 = *(const float2*)(P.biasB + lane * 2);
  float vx = tanhf(a.x + b.x + b1.x + b2.x);
  float vy = tanhf(a.y + b.y + b1.y + b2.y);
  int bb = batch[wave];
  float* p = pool + (size_t)bb * 128 + lane * 2;
  unsafeAtomicAdd(p, vx);
  unsafeAtomicAdd(p + 1, vy);
}

// ---------- final: counts via binary search over the SORTED batch arrays ----
__device__ __forceinline__ int lower_bound_i(const int* __restrict__ a, int n,
                                             int v) {
  int lo = 0, hi = n;
  while (lo < hi) {
    int mid = (lo + hi) >> 1;
    if (a[mid] < v) lo = mid + 1; else hi = mid;
  }
  return lo;
}

__global__ void final_k(const float* __restrict__ pool_i,
                        const int* __restrict__ batch_i,
                        const float* __restrict__ pool_j,
                        const int* __restrict__ batch_j, int N,
                        const float* __restrict__ lin_w,
                        const float* __restrict__ lin_b,
                        float* __restrict__ out) {
  int b = threadIdx.x;  // 256
  float ci = (float)(lower_bound_i(batch_i, N, b + 1) -
                     lower_bound_i(batch_i, N, b));
  float cj = (float)(lower_bound_i(batch_j, N, b + 1) -
                     lower_bound_i(batch_j, N, b));
  ci = fmaxf(ci, 1.f);
  cj = fmaxf(cj, 1.f);
  float acc = 0.f;
  #pragma unroll 4
  for (int f = 0; f < 128; ++f) {
    float x = 0.5f * (pool_i[(size_t)b * 128 + f] / ci +
                      pool_j[(size_t)b * 128 + f] / cj);
    acc += x * lin_w[f];
  }
  acc += lin_b[0];
  out[b] = 1.f / (1.f + __expf(-acc));
}

extern "C" void kernel_launch(void* const* d_in, const int* in_sizes, int n_in,
                              void* d_out, int out_size, void* d_ws,
                              size_t ws_size, hipStream_t stream) {
  const float* x_i = (const float*)d_in[0];
  const float* x_j = (const float*)d_in[1];
  const int* ei_arr[4] = {(const int*)d_in[2], (const int*)d_in[3],
                          (const int*)d_in[4], (const int*)d_in[5]};  // ii,jj,ij,ji
  const int* batch_i = (const int*)d_in[6];
  const int* batch_j = (const int*)d_in[7];
  const float* Ws = (const float*)d_in[8];
  const float* Wd = (const float*)d_in[9];
  const float* att_s = (const float*)d_in[10];
  const float* att_d = (const float*)d_in[11];
  const float* bias = (const float*)d_in[12];
  const float* lin_w = (const float*)d_in[13];
  const float* lin_b = (const float*)d_in[14];
  float* out = (float*)d_out;

  const int N = in_sizes[0] / 128;   // 100000
  const int E = in_sizes[2] / 2;     // 800000
  const size_t NF = (size_t)N * 128;

  char* w = (char*)d_ws;
  auto alloc = [&](size_t bytes) {
    char* p = w;
    w += (bytes + 255) & ~(size_t)255;
    return p;
  };
  unsigned short* bufA_i = (unsigned short*)alloc(NF * 2);
  unsigned short* bufA_j = (unsigned short*)alloc(NF * 2);
  unsigned char* hsb[4];
  for (int c = 0; c < 4; ++c) hsb[c] = (unsigned char*)alloc(NF);
  int* rowptr = (int*)alloc((size_t)4 * (N + 1) * 4);
  int* deg = (int*)alloc((size_t)4 * N * 4);
  int* fillc = (int*)alloc((size_t)4 * N * 4);
  int* epos = (int*)alloc((size_t)4 * E * 4);
  uint2* spcsr = (uint2*)alloc((size_t)4 * E * 8);
  float* asb[4];
  for (int c = 0; c < 4; ++c) asb[c] = (float*)alloc((size_t)N * 4);
  float* adb[4];
  for (int c = 0; c < 4; ++c) adb[c] = (float*)alloc((size_t)N * 4);
  float* wdad = (float*)alloc(8 * 128 * 4);
  unsigned short* Wst = (unsigned short*)alloc(8 * 16384 * 2);
  float* pool = (float*)alloc(2 * 256 * 128 * 4);
  float* pool_i = pool;
  float* pool_j = pool + 256 * 128;

  // ---- one-time prep ----
  w_to_bf16t<<<8, 256, 0, stream>>>(Ws, Wst);
  precompute_wa<<<8, 128, 0, stream>>>(Wd, att_d, wdad);

  // ---- CSR build (edge lists shared by both layers) ----
  hipMemsetAsync(deg, 0, (size_t)4 * N * 4, stream);
  hipMemsetAsync(fillc, 0, (size_t)4 * N * 4, stream);
  dim3 egrid(512, 4);
  hist4<<<egrid, 256, 0, stream>>>(ei_arr[0], ei_arr[1], ei_arr[2], ei_arr[3],
                                   E, deg, N);
  scan4<<<4, 1024, 0, stream>>>(deg, rowptr, N);
  fill4<<<egrid, 256, 0, stream>>>(ei_arr[0], ei_arr[1], ei_arr[2], ei_arr[3],
                                   E, rowptr, fillc, epos, N);

  hipMemsetAsync(pool, 0, 2 * 256 * 128 * 4, stream);

  const int gemm_blocks = (N + 63) / 64;
  const int nodew_blocks = (N + 3) / 4;   // one wave per node

  // conv c0 = ii (src i, dst i); c1 = jj (src j, dst j);
  // conv c2 = ij (src i, dst j); c3 = ji (src j, dst i).
  // pair0: out_i <- convs {c0, c3}; pair1: out_j <- {c1, c2}.
  for (int l = 0; l < 2; ++l) {
    const void* cur_i = (l == 0) ? (const void*)x_i : (const void*)bufA_i;
    const void* cur_j = (l == 0) ? (const void*)x_j : (const void*)bufA_j;
    const size_t L = (size_t)l * 4;

    GemmArgs Ga = {Wst + (L + 0) * 16384, att_s + (L + 0) * 128, hsb[0], asb[0],
                   Wst + (L + 2) * 16384, att_s + (L + 2) * 128, hsb[2], asb[2],
                   wdad + (L + 0) * 128, wdad + (L + 3) * 128, adb[0], adb[3]};
    GemmArgs Gb = {Wst + (L + 1) * 16384, att_s + (L + 1) * 128, hsb[1], asb[1],
                   Wst + (L + 3) * 16384, att_s + (L + 3) * 128, hsb[3], asb[3],
                   wdad + (L + 1) * 128, wdad + (L + 2) * 128, adb[1], adb[2]};
    dim3 ggrid(gemm_blocks, 2);
    if (l == 0) {
      gemm_dual2<0><<<ggrid, 256, 0, stream>>>(cur_i, cur_j, Ga, Gb, N);
    } else {
      gemm_dual2<1><<<ggrid, 256, 0, stream>>>(cur_i, cur_j, Ga, Gb, N);
    }

    edge_p4<<<egrid, 256, 0, stream>>>(
        ei_arr[0], ei_arr[1], ei_arr[2], ei_arr[3], E, epos,
        asb[0], asb[1], asb[2], asb[3],
        adb[0], adb[1], adb[2], adb[3], spcsr);

    PairArgs P0 = {rowptr + (size_t)0 * (N + 1), spcsr + (size_t)0 * E, hsb[0],
                   rowptr + (size_t)3 * (N + 1), spcsr + (size_t)3 * E, hsb[3],
                   bias + (L + 0) * 128, bias + (L + 3) * 128};
    PairArgs P1 = {rowptr + (size_t)1 * (N + 1), spcsr + (size_t)1 * E, hsb[1],
                   rowptr + (size_t)2 * (N + 1), spcsr + (size_t)2 * E, hsb[2],
                   bias + (L + 1) * 128, bias + (L + 2) * 128};

    dim3 agrid(nodew_blocks, 2);
    if (l == 0) {
      agg_store2<<<agrid, 256, 0, stream>>>(P0, bufA_i, P1, bufA_j, N);
    } else {
      agg_pool2<<<agrid, 256, 0, stream>>>(P0, batch_i, pool_i, P1, batch_j,
                                           pool_j, N);
    }
  }

  final_k<<<1, 256, 0, stream>>>(pool_i, batch_i, pool_j, batch_j, N, lin_w,
                                 lin_b, out);
}

// Round 15
// 1031.552 us; speedup vs baseline: 2.0136x; 1.0714x over previous
//
#include <hip/hip_runtime.h>

// HeteroGNN: 2 layers x 4 GATConv (single head), N=100000, E=800000, C=128.
// R15 = R12 verbatim (session best, 1039us): wave/node interleaved-pair agg
// with inline scores + csrc + readlane broadcast + fp8-e4m3 hs rows (128B);
// MFMA bf16 gemm_dual2 with as/ad epilogues; binary-search pool counts.
// R14's {s,p} precompute reverted (neutral agg + 65us edge_p4 overhead).
// Agg is bound by random 128B row-gather throughput (uniform-random graph,
// no locality): byte reduction was the only lever that moved it (bf16->fp8).

#define NEG_SLOPE 0.2f

typedef __attribute__((ext_vector_type(8))) short short8v;
typedef __attribute__((ext_vector_type(4))) float float4v;
typedef __attribute__((ext_vector_type(2))) float float2v;

__device__ __forceinline__ unsigned short f2bf(float f) {
  unsigned u = __float_as_uint(f);
  unsigned r = (u + 0x7FFFu + ((u >> 16) & 1u)) >> 16;
  return (unsigned short)r;
}
__device__ __forceinline__ unsigned pack2(float a, float b) {
  return (unsigned)f2bf(a) | ((unsigned)f2bf(b) << 16);
}
__device__ __forceinline__ float bflo(unsigned u) {
  return __uint_as_float(u << 16);
}
__device__ __forceinline__ float bfhi(unsigned u) {
  return __uint_as_float(u & 0xFFFF0000u);
}
__device__ __forceinline__ float rl_f(float x, int lane) {
  return __int_as_float(__builtin_amdgcn_readlane(__float_as_int(x), lane));
}
__device__ __forceinline__ int rl_i(int x, int lane) {
  return __builtin_amdgcn_readlane(x, lane);
}

// ---------- W -> bf16 transposed (Wt[n][k] = W[k][n]), 8 matrices ----------
__global__ __launch_bounds__(256) void w_to_bf16t(const float* __restrict__ W,
                                                  unsigned short* __restrict__ Wt) {
  __shared__ float buf[64][129];
  int b = blockIdx.x, t = threadIdx.x;
  const float* w = W + (size_t)b * 16384;
  unsigned short* o = Wt + (size_t)b * 16384;
  for (int h = 0; h < 2; ++h) {
    for (int i = 0; i < 32; ++i) {
      int idx = i * 256 + t;
      buf[idx >> 7][idx & 127] = w[(size_t)(h * 64 + (idx >> 7)) * 128 + (idx & 127)];
    }
    __syncthreads();
    for (int i = 0; i < 32; ++i) {
      int idx = i * 256 + t;
      o[(size_t)(idx >> 6) * 128 + h * 64 + (idx & 63)] = f2bf(buf[idx & 63][idx >> 6]);
    }
    __syncthreads();
  }
}

// ---------- precompute (Wd @ a_d) for all 8 (layer,conv) ----------
__global__ void precompute_wa(const float* __restrict__ W,
                              const float* __restrict__ att,
                              float* __restrict__ out) {
  int idx = blockIdx.x;   // 0..7
  int f = threadIdx.x;    // 0..127
  const float* w = W + (size_t)idx * 128 * 128 + (size_t)f * 128;
  const float* a = att + idx * 128;
  float s = 0.f;
  #pragma unroll 8
  for (int h = 0; h < 128; ++h) s += w[h] * a[h];
  out[idx * 128 + f] = s;
}

// ---------- args for one dual GEMM ----------
struct GemmArgs {
  const unsigned short* Wt1; const float* att1;
  unsigned char* Hb1; float* as1;
  const unsigned short* Wt2; const float* att2;
  unsigned char* Hb2; float* as2;
  const float* vdA; const float* vdB;
  float* adA; float* adB;
};

// ---------- merged MFMA dual GEMM (fp8 hs out, f32 accum) ----------
template <int XBF16>
__global__ __launch_bounds__(256) void gemm_dual2(
    const void* __restrict__ X0, const void* __restrict__ X1,
    GemmArgs Ga, GemmArgs Gb, int M) {
  __shared__ unsigned short Xt[64][136];    // [row][k], bf16, padded
  __shared__ unsigned short Wt[128][136];   // [n][k], bf16, padded
  const int t = threadIdx.x;
  const int row0 = blockIdx.x * 64;
  const void* Xv = blockIdx.y ? X1 : X0;
  const GemmArgs& G = blockIdx.y ? Gb : Ga;

  // stage X tile as bf16
  {
    int r = t >> 2;
    int cq = (t & 3) * 32;
    int gr = row0 + r;
    if (gr >= M) gr = M - 1;
    if (XBF16) {
      const unsigned short* Xb = (const unsigned short*)Xv;
      const uint4* src = (const uint4*)(Xb + (size_t)gr * 128 + cq);
      #pragma unroll
      for (int i = 0; i < 4; ++i) *(uint4*)&Xt[r][cq + i * 8] = src[i];
    } else {
      const float* Xf = (const float*)Xv;
      const float4* src = (const float4*)(Xf + (size_t)gr * 128 + cq);
      #pragma unroll
      for (int i = 0; i < 8; ++i) {
        float4 v = src[i];
        uint2 u;
        u.x = pack2(v.x, v.y);
        u.y = pack2(v.z, v.w);
        *(uint2*)&Xt[r][cq + i * 4] = u;
      }
    }
  }
  // stage W1
  {
    int n = t >> 1;
    int kh = (t & 1) * 64;
    const uint4* src = (const uint4*)(G.Wt1 + (size_t)n * 128 + kh);
    #pragma unroll
    for (int i = 0; i < 8; ++i) *(uint4*)&Wt[n][kh + i * 8] = src[i];
  }
  __syncthreads();

  // ad epilogue: rows 0..63 dot vdA (threads 0-63) / vdB (threads 64-127)
  if (t < 128) {
    int r = t & 63;
    const float* vd = (t < 64) ? G.vdA : G.vdB;
    float* adout = (t < 64) ? G.adA : G.adB;
    float sum = 0.f;
    #pragma unroll 4
    for (int k8 = 0; k8 < 16; ++k8) {
      uint4 u = *(const uint4*)&Xt[r][k8 * 8];
      const float* v = vd + k8 * 8;
      sum = fmaf(bflo(u.x), v[0], sum);
      sum = fmaf(bfhi(u.x), v[1], sum);
      sum = fmaf(bflo(u.y), v[2], sum);
      sum = fmaf(bfhi(u.y), v[3], sum);
      sum = fmaf(bflo(u.z), v[4], sum);
      sum = fmaf(bfhi(u.z), v[5], sum);
      sum = fmaf(bflo(u.w), v[6], sum);
      sum = fmaf(bfhi(u.w), v[7], sum);
    }
    int gr = row0 + r;
    if (gr < M) adout[gr] = sum;
  }

  const int lane = t & 63;
  const int wv = t >> 6;          // wave 0..3 -> rows ws..ws+15
  const int m = lane & 15;        // A-row / B-col / D-col
  const int g = lane >> 4;        // k-chunk group; D-rows g*4..g*4+3
  const int ws = wv * 16;

  for (int ww = 0; ww < 2; ++ww) {
    if (ww == 1) {
      __syncthreads();            // everyone done with W1
      int n = t >> 1;
      int kh = (t & 1) * 64;
      const uint4* src = (const uint4*)(G.Wt2 + (size_t)n * 128 + kh);
      #pragma unroll
      for (int i = 0; i < 8; ++i) *(uint4*)&Wt[n][kh + i * 8] = src[i];
      __syncthreads();
    }
    const float* att = ww ? G.att2 : G.att1;
    unsigned char* Hb = ww ? G.Hb2 : G.Hb1;
    float* as_ = ww ? G.as2 : G.as1;

    float4v acc[8];
    float4v z = {0.f, 0.f, 0.f, 0.f};
    #pragma unroll
    for (int nt = 0; nt < 8; ++nt) acc[nt] = z;

    #pragma unroll
    for (int ks = 0; ks < 4; ++ks) {
      short8v a = *(const short8v*)&Xt[ws + m][ks * 32 + g * 8];
      #pragma unroll
      for (int nt = 0; nt < 8; ++nt) {
        short8v b = *(const short8v*)&Wt[nt * 16 + m][ks * 32 + g * 8];
        acc[nt] = __builtin_amdgcn_mfma_f32_16x16x32_bf16(a, b, acc[nt], 0, 0, 0);
      }
    }

    // as epilogue: as[row] = sum_col acc[row][col]*att[col]
    {
      float attv[8];
      #pragma unroll
      for (int nt = 0; nt < 8; ++nt) attv[nt] = att[nt * 16 + m];
      #pragma unroll
      for (int r = 0; r < 4; ++r) {
        float s = 0.f;
        #pragma unroll
        for (int nt = 0; nt < 8; ++nt) s = fmaf(acc[nt][r], attv[nt], s);
        #pragma unroll
        for (int off = 1; off < 16; off <<= 1) s += __shfl_xor(s, off);
        if (m == 0) {
          int grow = row0 + ws + g * 4 + r;
          if (grow < M) as_[grow] = s;
        }
      }
    }

    // hs store: fp8 e4m3, pack adjacent-col pairs via lane shuffle
    #pragma unroll
    for (int nt = 0; nt < 8; ++nt) {
      #pragma unroll
      for (int r = 0; r < 4; ++r) {
        float v = acc[nt][r];
        float vn = __shfl_xor(v, 1);
        if ((m & 1) == 0) {
          int grow = row0 + ws + g * 4 + r;
          if (grow < M) {
            int pk = __builtin_amdgcn_cvt_pk_fp8_f32(v, vn, 0, false);
            *(unsigned short*)(Hb + (size_t)grow * 128 + nt * 16 + m) =
                (unsigned short)(pk & 0xFFFF);
          }
        }
      }
    }
  }
}

// ---------- CSR build ----------
__global__ void hist4(const int* __restrict__ e0, const int* __restrict__ e1,
                      const int* __restrict__ e2, const int* __restrict__ e3,
                      int E, int* __restrict__ deg, int N) {
  int t = blockIdx.y;
  const int* ei = (t == 0) ? e0 : (t == 1) ? e1 : (t == 2) ? e2 : e3;
  int stride = gridDim.x * 256;
  for (int i = blockIdx.x * 256 + threadIdx.x; i < E; i += stride)
    atomicAdd(&deg[t * N + ei[E + i]], 1);
}

__global__ __launch_bounds__(1024) void scan4(const int* __restrict__ deg,
                                              int* __restrict__ rowptr, int N) {
  __shared__ int sums[1024];
  int t = threadIdx.x;
  int ty = blockIdx.x;
  const int* d = deg + (size_t)ty * N;
  int* rp = rowptr + (size_t)ty * (N + 1);
  int chunk = (N + 1023) / 1024;
  int lo = t * chunk;
  int hi = lo + chunk; if (hi > N) hi = N; if (lo > N) lo = N;
  int s = 0;
  for (int i = lo; i < hi; ++i) s += d[i];
  sums[t] = s;
  __syncthreads();
  for (int off = 1; off < 1024; off <<= 1) {
    int add = (t >= off) ? sums[t - off] : 0;
    __syncthreads();
    sums[t] += add;
    __syncthreads();
  }
  int run = (t == 0) ? 0 : sums[t - 1];
  for (int i = lo; i < hi; ++i) {
    rp[i] = run;
    run += d[i];
  }
  if (t == 1023) rp[N] = sums[1023];
}

__global__ void fill4(const int* __restrict__ e0, const int* __restrict__ e1,
                      const int* __restrict__ e2, const int* __restrict__ e3,
                      int E, const int* __restrict__ rowptr,
                      int* __restrict__ fill, int* __restrict__ csrc, int N) {
  int t = blockIdx.y;
  const int* ei = (t == 0) ? e0 : (t == 1) ? e1 : (t == 2) ? e2 : e3;
  int stride = gridDim.x * 256;
  for (int i = blockIdx.x * 256 + threadIdx.x; i < E; i += stride) {
    int d = ei[E + i];
    int s = ei[i];
    int pos = rowptr[(size_t)t * (N + 1) + d] + atomicAdd(&fill[t * N + d], 1);
    csrc[(size_t)t * E + pos] = s;
  }
}

// ---------- args bundle for one conv-pair ----------
struct PairArgs {
  const int* rA; const int* sA; const unsigned char* hA;
  const float* asA; const float* adA;
  const int* rB; const int* sB; const unsigned char* hB;
  const float* asB; const float* adB;
  const float* biasA; const float* biasB;
};

// fp8x2 gather helper: 2 fp8 bytes -> 2 floats (HW convert)
#define GATH(P_h, idx, dst) {                                           \
  unsigned short uu = *(const unsigned short*)((P_h) + (size_t)(idx) * 128 + lane * 2); \
  dst = __builtin_amdgcn_cvt_pk_f32_fp8((int)uu, false); }

// ---------- interleaved dual-conv softmax agg (wave/node, 2 feats/lane) ------
__device__ __forceinline__ void agg_pair(const PairArgs& P, int n, int lane,
                                         float2& outA, float2& outB) {
  int begA = P.rA[n], endA = P.rA[n + 1];
  int begB = P.rB[n], endB = P.rB[n + 1];
  float adA = P.adA[n], adB = P.adB[n];
  float lsA = 0.f, lsB = 0.f;
  float2 aA = make_float2(0.f, 0.f), aB = make_float2(0.f, 0.f);
  int cA = begA, cB = begB;
  while (cA < endA || cB < endB) {
    int kA = cA + lane, kB = cB + lane;
    bool vA = kA < endA;
    bool vB = kB < endB;
    int sA = vA ? P.sA[kA] : 0;
    int sB = vB ? P.sB[kB] : 0;
    float eA = vA ? (P.asA[sA] + adA) : 0.f;
    float eB = vB ? (P.asB[sB] + adB) : 0.f;
    eA = eA > 0.f ? eA : NEG_SLOPE * eA;
    eB = eB > 0.f ? eB : NEG_SLOPE * eB;
    float pA = vA ? __expf(eA) : 0.f;
    float pB = vB ? __expf(eB) : 0.f;
    int cntA = endA - cA; cntA = cntA < 0 ? 0 : (cntA > 64 ? 64 : cntA);
    int cntB = endB - cB; cntB = cntB < 0 ? 0 : (cntB > 64 ? 64 : cntB);
    int cnt = cntA > cntB ? cntA : cntB;
    for (int base = 0; base < cnt; base += 8) {
      float qa0 = rl_f(pA, base + 0), qa1 = rl_f(pA, base + 1);
      float qa2 = rl_f(pA, base + 2), qa3 = rl_f(pA, base + 3);
      float qa4 = rl_f(pA, base + 4), qa5 = rl_f(pA, base + 5);
      float qa6 = rl_f(pA, base + 6), qa7 = rl_f(pA, base + 7);
      float qb0 = rl_f(pB, base + 0), qb1 = rl_f(pB, base + 1);
      float qb2 = rl_f(pB, base + 2), qb3 = rl_f(pB, base + 3);
      float qb4 = rl_f(pB, base + 4), qb5 = rl_f(pB, base + 5);
      float qb6 = rl_f(pB, base + 6), qb7 = rl_f(pB, base + 7);
      int ta0 = rl_i(sA, base + 0), ta1 = rl_i(sA, base + 1);
      int ta2 = rl_i(sA, base + 2), ta3 = rl_i(sA, base + 3);
      int ta4 = rl_i(sA, base + 4), ta5 = rl_i(sA, base + 5);
      int ta6 = rl_i(sA, base + 6), ta7 = rl_i(sA, base + 7);
      int tb0 = rl_i(sB, base + 0), tb1 = rl_i(sB, base + 1);
      int tb2 = rl_i(sB, base + 2), tb3 = rl_i(sB, base + 3);
      int tb4 = rl_i(sB, base + 4), tb5 = rl_i(sB, base + 5);
      int tb6 = rl_i(sB, base + 6), tb7 = rl_i(sB, base + 7);
      float2v ha0, ha1, ha2, ha3, ha4, ha5, ha6, ha7;
      float2v hb0, hb1, hb2, hb3, hb4, hb5, hb6, hb7;
      GATH(P.hA, ta0, ha0) GATH(P.hA, ta1, ha1)
      GATH(P.hA, ta2, ha2) GATH(P.hA, ta3, ha3)
      GATH(P.hA, ta4, ha4) GATH(P.hA, ta5, ha5)
      GATH(P.hA, ta6, ha6) GATH(P.hA, ta7, ha7)
      GATH(P.hB, tb0, hb0) GATH(P.hB, tb1, hb1)
      GATH(P.hB, tb2, hb2) GATH(P.hB, tb3, hb3)
      GATH(P.hB, tb4, hb4) GATH(P.hB, tb5, hb5)
      GATH(P.hB, tb6, hb6) GATH(P.hB, tb7, hb7)
      lsA += ((qa0 + qa1) + (qa2 + qa3)) + ((qa4 + qa5) + (qa6 + qa7));
      lsB += ((qb0 + qb1) + (qb2 + qb3)) + ((qb4 + qb5) + (qb6 + qb7));
      aA.x = fmaf(qa0, ha0[0], aA.x); aA.y = fmaf(qa0, ha0[1], aA.y);
      aA.x = fmaf(qa1, ha1[0], aA.x); aA.y = fmaf(qa1, ha1[1], aA.y);
      aA.x = fmaf(qa2, ha2[0], aA.x); aA.y = fmaf(qa2, ha2[1], aA.y);
      aA.x = fmaf(qa3, ha3[0], aA.x); aA.y = fmaf(qa3, ha3[1], aA.y);
      aA.x = fmaf(qa4, ha4[0], aA.x); aA.y = fmaf(qa4, ha4[1], aA.y);
      aA.x = fmaf(qa5, ha5[0], aA.x); aA.y = fmaf(qa5, ha5[1], aA.y);
      aA.x = fmaf(qa6, ha6[0], aA.x); aA.y = fmaf(qa6, ha6[1], aA.y);
      aA.x = fmaf(qa7, ha7[0], aA.x); aA.y = fmaf(qa7, ha7[1], aA.y);
      aB.x = fmaf(qb0, hb0[0], aB.x); aB.y = fmaf(qb0, hb0[1], aB.y);
      aB.x = fmaf(qb1, hb1[0], aB.x); aB.y = fmaf(qb1, hb1[1], aB.y);
      aB.x = fmaf(qb2, hb2[0], aB.x); aB.y = fmaf(qb2, hb2[1], aB.y);
      aB.x = fmaf(qb3, hb3[0], aB.x); aB.y = fmaf(qb3, hb3[1], aB.y);
      aB.x = fmaf(qb4, hb4[0], aB.x); aB.y = fmaf(qb4, hb4[1], aB.y);
      aB.x = fmaf(qb5, hb5[0], aB.x); aB.y = fmaf(qb5, hb5[1], aB.y);
      aB.x = fmaf(qb6, hb6[0], aB.x); aB.y = fmaf(qb6, hb6[1], aB.y);
      aB.x = fmaf(qb7, hb7[0], aB.x); aB.y = fmaf(qb7, hb7[1], aB.y);
    }
    cA += 64;
    cB += 64;
  }
  float invA = 1.f / fmaxf(lsA, 1e-16f);
  float invB = 1.f / fmaxf(lsB, 1e-16f);
  outA = make_float2(aA.x * invA, aA.y * invA);
  outB = make_float2(aB.x * invB, aB.y * invB);
}

// ---------- merged layer-1: both pairs in one dispatch (blockIdx.y) ----------
__global__ __launch_bounds__(256) void agg_store2(
    PairArgs P0, unsigned short* __restrict__ out0,
    PairArgs P1, unsigned short* __restrict__ out1, int N) {
  int wave = (blockIdx.x * 256 + threadIdx.x) >> 6;
  int lane = threadIdx.x & 63;
  if (wave >= N) return;
  const PairArgs& P = blockIdx.y ? P1 : P0;
  unsigned short* out = blockIdx.y ? out1 : out0;
  float2 a, b;
  agg_pair(P, wave, lane, a, b);
  float2 b1 = *(const float2*)(P.biasA + lane * 2);
  float2 b2 = *(const float2*)(P.biasB + lane * 2);
  float vx = tanhf(a.x + b.x + b1.x + b2.x);
  float vy = tanhf(a.y + b.y + b1.y + b2.y);
  *(unsigned*)(out + (size_t)wave * 128 + lane * 2) = pack2(vx, vy);
}

// ---------- merged layer-2: both pairs, pooled directly (atomic) ----------
__global__ __launch_bounds__(256) void agg_pool2(
    PairArgs P0, const int* __restrict__ batch0, float* __restrict__ pool0,
    PairArgs P1, const int* __restrict__ batch1, float* __restrict__ pool1,
    int N) {
  int wave = (blockIdx.x * 256 + threadIdx.x) >> 6;
  int lane = threadIdx.x & 63;
  if (wave >= N) return;
  const PairArgs& P = blockIdx.y ? P1 : P0;
  const int* batch = blockIdx.y ? batch1 : batch0;
  float* pool = blockIdx.y ? pool1 : pool0;
  float2 a, b;
  agg_pair(P, wave, lane, a, b);
  float2 b1 = *(const float2*)(P.biasA + lane * 2);
  float2 b2 = *(const float2*)(P.biasB + lane * 2);
  float vx = tanhf(a.x + b.x + b1.x + b2.x);
  float vy = tanhf(a.y + b.y + b1.y + b2.y);
  int bb = batch[wave];
  float* p = pool + (size_t)bb * 128 + lane * 2;
  unsafeAtomicAdd(p, vx);
  unsafeAtomicAdd(p + 1, vy);
}

// ---------- final: counts via binary search over the SORTED batch arrays ----
__device__ __forceinline__ int lower_bound_i(const int* __restrict__ a, int n,
                                             int v) {
  int lo = 0, hi = n;
  while (lo < hi) {
    int mid = (lo + hi) >> 1;
    if (a[mid] < v) lo = mid + 1; else hi = mid;
  }
  return lo;
}

__global__ void final_k(const float* __restrict__ pool_i,
                        const int* __restrict__ batch_i,
                        const float* __restrict__ pool_j,
                        const int* __restrict__ batch_j, int N,
                        const float* __restrict__ lin_w,
                        const float* __restrict__ lin_b,
                        float* __restrict__ out) {
  int b = threadIdx.x;  // 256
  float ci = (float)(lower_bound_i(batch_i, N, b + 1) -
                     lower_bound_i(batch_i, N, b));
  float cj = (float)(lower_bound_i(batch_j, N, b + 1) -
                     lower_bound_i(batch_j, N, b));
  ci = fmaxf(ci, 1.f);
  cj = fmaxf(cj, 1.f);
  float acc = 0.f;
  #pragma unroll 4
  for (int f = 0; f < 128; ++f) {
    float x = 0.5f * (pool_i[(size_t)b * 128 + f] / ci +
                      pool_j[(size_t)b * 128 + f] / cj);
    acc += x * lin_w[f];
  }
  acc += lin_b[0];
  out[b] = 1.f / (1.f + __expf(-acc));
}

extern "C" void kernel_launch(void* const* d_in, const int* in_sizes, int n_in,
                              void* d_out, int out_size, void* d_ws,
                              size_t ws_size, hipStream_t stream) {
  const float* x_i = (const float*)d_in[0];
  const float* x_j = (const float*)d_in[1];
  const int* ei_arr[4] = {(const int*)d_in[2], (const int*)d_in[3],
                          (const int*)d_in[4], (const int*)d_in[5]};  // ii,jj,ij,ji
  const int* batch_i = (const int*)d_in[6];
  const int* batch_j = (const int*)d_in[7];
  const float* Ws = (const float*)d_in[8];
  const float* Wd = (const float*)d_in[9];
  const float* att_s = (const float*)d_in[10];
  const float* att_d = (const float*)d_in[11];
  const float* bias = (const float*)d_in[12];
  const float* lin_w = (const float*)d_in[13];
  const float* lin_b = (const float*)d_in[14];
  float* out = (float*)d_out;

  const int N = in_sizes[0] / 128;   // 100000
  const int E = in_sizes[2] / 2;     // 800000
  const size_t NF = (size_t)N * 128;

  char* w = (char*)d_ws;
  auto alloc = [&](size_t bytes) {
    char* p = w;
    w += (bytes + 255) & ~(size_t)255;
    return p;
  };
  unsigned short* bufA_i = (unsigned short*)alloc(NF * 2);
  unsigned short* bufA_j = (unsigned short*)alloc(NF * 2);
  unsigned char* hsb[4];
  for (int c = 0; c < 4; ++c) hsb[c] = (unsigned char*)alloc(NF);
  int* csrc = (int*)alloc((size_t)4 * E * 4);
  int* rowptr = (int*)alloc((size_t)4 * (N + 1) * 4);
  int* deg = (int*)alloc((size_t)4 * N * 4);
  int* fillc = (int*)alloc((size_t)4 * N * 4);
  float* asb[4];
  for (int c = 0; c < 4; ++c) asb[c] = (float*)alloc((size_t)N * 4);
  float* adb[4];
  for (int c = 0; c < 4; ++c) adb[c] = (float*)alloc((size_t)N * 4);
  float* wdad = (float*)alloc(8 * 128 * 4);
  unsigned short* Wst = (unsigned short*)alloc(8 * 16384 * 2);
  float* pool = (float*)alloc(2 * 256 * 128 * 4);
  float* pool_i = pool;
  float* pool_j = pool + 256 * 128;

  // ---- one-time prep ----
  w_to_bf16t<<<8, 256, 0, stream>>>(Ws, Wst);
  precompute_wa<<<8, 128, 0, stream>>>(Wd, att_d, wdad);

  // ---- CSR build (edge lists shared by both layers) ----
  hipMemsetAsync(deg, 0, (size_t)4 * N * 4, stream);
  hipMemsetAsync(fillc, 0, (size_t)4 * N * 4, stream);
  dim3 egrid(512, 4);
  hist4<<<egrid, 256, 0, stream>>>(ei_arr[0], ei_arr[1], ei_arr[2], ei_arr[3],
                                   E, deg, N);
  scan4<<<4, 1024, 0, stream>>>(deg, rowptr, N);
  fill4<<<egrid, 256, 0, stream>>>(ei_arr[0], ei_arr[1], ei_arr[2], ei_arr[3],
                                   E, rowptr, fillc, csrc, N);

  hipMemsetAsync(pool, 0, 2 * 256 * 128 * 4, stream);

  const int gemm_blocks = (N + 63) / 64;
  const int nodew_blocks = (N + 3) / 4;   // one wave per node

  // conv c0 = ii (src i, dst i); c1 = jj (src j, dst j);
  // conv c2 = ij (src i, dst j); c3 = ji (src j, dst i).
  // pair0: out_i <- convs {c0, c3}; pair1: out_j <- {c1, c2}.
  for (int l = 0; l < 2; ++l) {
    const void* cur_i = (l == 0) ? (const void*)x_i : (const void*)bufA_i;
    const void* cur_j = (l == 0) ? (const void*)x_j : (const void*)bufA_j;
    const size_t L = (size_t)l * 4;

    GemmArgs Ga = {Wst + (L + 0) * 16384, att_s + (L + 0) * 128, hsb[0], asb[0],
                   Wst + (L + 2) * 16384, att_s + (L + 2) * 128, hsb[2], asb[2],
                   wdad + (L + 0) * 128, wdad + (L + 3) * 128, adb[0], adb[3]};
    GemmArgs Gb = {Wst + (L + 1) * 16384, att_s + (L + 1) * 128, hsb[1], asb[1],
                   Wst + (L + 3) * 16384, att_s + (L + 3) * 128, hsb[3], asb[3],
                   wdad + (L + 1) * 128, wdad + (L + 2) * 128, adb[1], adb[2]};
    dim3 ggrid(gemm_blocks, 2);
    if (l == 0) {
      gemm_dual2<0><<<ggrid, 256, 0, stream>>>(cur_i, cur_j, Ga, Gb, N);
    } else {
      gemm_dual2<1><<<ggrid, 256, 0, stream>>>(cur_i, cur_j, Ga, Gb, N);
    }

    PairArgs P0 = {rowptr + (size_t)0 * (N + 1), csrc + (size_t)0 * E, hsb[0],
                   asb[0], adb[0],
                   rowptr + (size_t)3 * (N + 1), csrc + (size_t)3 * E, hsb[3],
                   asb[3], adb[3],
                   bias + (L + 0) * 128, bias + (L + 3) * 128};
    PairArgs P1 = {rowptr + (size_t)1 * (N + 1), csrc + (size_t)1 * E, hsb[1],
                   asb[1], adb[1],
                   rowptr + (size_t)2 * (N + 1), csrc + (size_t)2 * E, hsb[2],
                   asb[2], adb[2],
                   bias + (L + 1) * 128, bias + (L + 2) * 128};

    dim3 agrid(nodew_blocks, 2);
    if (l == 0) {
      agg_store2<<<agrid, 256, 0, stream>>>(P0, bufA_i, P1, bufA_j, N);
    } else {
      agg_pool2<<<agrid, 256, 0, stream>>>(P0, batch_i, pool_i, P1, batch_j,
                                           pool_j, N);
    }
  }

  final_k<<<1, 256, 0, stream>>>(pool_i, batch_i, pool_j, batch_j, N, lin_w,
                                 lin_b, out);
}